// Round 2
// baseline (191.084 us; speedup 1.0000x reference)
//
#include <hip/hip_runtime.h>

// Disable FMA contraction for the entire TU so IoU/decoding produce
// bitwise-identical results in both kernels (the top-dk selection uses
// strict > against the threshold, so bit-exactness matters).
#pragma clang fp contract(off)

#define IMG_W 640
#define IMG_H 384
#define NBOX 64
#define BS 4
#define PAIR_STRIDE 16
#define CAP 12544   // 112*112 >= worst-case region cells (<=103*103)

// IoU exactly as reference _boxes_iou.
__device__ __forceinline__ float iou_one(float cx, float cy, float w, float h,
                                         float gcx, float gcy, float gw, float gh) {
    float b1minx = cx - w / 2.0f;
    float b1maxx = cx + w / 2.0f;
    float b1miny = cy - h / 2.0f;
    float b1maxy = cy + h / 2.0f;
    float b2minx = gcx - gw / 2.0f;
    float b2maxx = gcx + gw / 2.0f;
    float b2miny = gcy - gh / 2.0f;
    float b2maxy = gcy + gh / 2.0f;
    float iw = fmaxf(fminf(b1maxx, b2maxx) - fmaxf(b1minx, b2minx), 0.0f);
    float ih = fmaxf(fminf(b1maxy, b2maxy) - fmaxf(b1miny, b2miny), 0.0f);
    float inter = iw * ih;
    float uni = w * h + gw * gh - inter;
    uni = fmaxf(uni, 1e-6f);
    return inter / uni;
}

// Decode one cell exactly as reference _decode.
__device__ __forceinline__ void decode_cell(const float* __restrict__ pred, int b,
                                            int hh, int ww,
                                            float& cx, float& cy, float& w, float& h) {
    const int HW = IMG_H * IMG_W;
    int base = ((b * 4) * IMG_H + hh) * IMG_W + ww;
    float p0 = pred[base];
    float p1 = pred[base + HW];
    float p2 = pred[base + 2 * HW];
    float p3 = pred[base + 3 * HW];
    float rx = ((float)ww + 0.5f) * 2.0f;   // (w+0.5)*(MODEL_W/W) = *2.0
    float ry = ((float)hh + 0.5f) * 2.0f;
    float x1 = p0 * 80.0f + rx;
    float y1 = p1 * 80.0f + ry;
    float x2 = p2 * 80.0f + rx;
    float y2 = p3 * 80.0f + ry;
    w = x2 - x1;
    h = y2 - y1;
    cx = x1 + w / 2.0f;
    cy = y1 + h / 2.0f;
}

// One block per (b, n) pair: compute region IoUs, sum -> dk, exact radix
// select of the rank-dk value (0-indexed, descending), store descriptor.
__global__ __launch_bounds__(256) void pair_kernel(const float* __restrict__ pred,
                                                   const float* __restrict__ bboxes,
                                                   const int* __restrict__ dmode,
                                                   float* __restrict__ pairws) {
    __shared__ float vals[CAP];
    __shared__ unsigned hist[256];
    __shared__ float redf[4];
    __shared__ unsigned redu[4];
    __shared__ int sb_bucket, sb_r;

    const int pair = blockIdx.x;
    const int b = pair >> 6;
    const int tid = threadIdx.x;

    const float* box = bboxes + pair * 6;
    float gx1 = box[0], gy1 = box[1], gx2 = box[2], gy2 = box[3];
    float gcls = box[4], gdiff = box[5];
    float gbw = gx2 - gx1;
    float gbh = gy2 - gy1;
    float gcx = gx1 + gbw / 2.0f;
    float gcy = gy1 + gbh / 2.0f;
    bool valid = (gbw * gbh) != 0.0f;

    // Region bounds, replicating reference float op order exactly.
    float mwf = floorf(fmaxf(gx1 * 640.0f / 1280.0f - 0.5f, 0.0f));
    float Mwf = ceilf(fminf(gx2 * 640.0f / 1280.0f - 0.5f, 639.0f));
    float mhf = floorf(fmaxf(gy1 * 384.0f / 768.0f - 0.5f, 0.0f));
    float Mhf = ceilf(fminf(gy2 * 384.0f / 768.0f - 0.5f, 383.0f));
    int wlo = (int)mwf, whi = (int)Mwf, hlo = (int)mhf, hhi = (int)Mhf;
    int rw = whi - wlo + 1;
    int rh = hhi - hlo + 1;
    int area = (valid && rw > 0 && rh > 0) ? rw * rh : 0;
    if (area > CAP) area = CAP;   // cannot trigger for harness inputs (<=10609)

    float lsum = 0.0f;
    unsigned lpos = 0;
    for (int i = tid; i < area; i += 256) {
        int hh = hlo + i / rw;
        int ww = wlo + i % rw;
        float cx, cy, pw, ph;
        decode_cell(pred, b, hh, ww, cx, cy, pw, ph);
        float v = iou_one(cx, cy, pw, ph, gcx, gcy, gbw, gbh);
        vals[i] = v;
        lsum += v;
        lpos += (v > 0.0f) ? 1u : 0u;
    }
    // wave reduce (64 lanes) then cross-wave via LDS
    for (int off = 32; off > 0; off >>= 1) {
        lsum += __shfl_down(lsum, off, 64);
        lpos += __shfl_down(lpos, off, 64);
    }
    int wave = tid >> 6;
    if ((tid & 63) == 0) { redf[wave] = lsum; redu[wave] = lpos; }
    __syncthreads();
    if (tid == 0) {
        redf[0] = redf[0] + redf[1] + redf[2] + redf[3];
        redu[0] = redu[0] + redu[1] + redu[2] + redu[3];
    }
    __syncthreads();
    float sum = redf[0];
    unsigned npos = redu[0];
    int dk = (int)ceilf(fmaxf(sum, 1.0f));

    // Exact threshold: rank-dk (0-indexed desc) over full H*W array = positives
    // then zeros. If dk >= npos the threshold is 0.
    float thr = 0.0f;
    if ((unsigned)dk < npos) {
        unsigned prefix = 0;
        unsigned r = (unsigned)dk;
        for (int shift = 24; shift >= 0; shift -= 8) {
            for (int i = tid; i < 256; i += 256) hist[i] = 0;
            __syncthreads();
            unsigned maskhi = (shift == 24) ? 0u : (0xFFFFFFFFu << (shift + 8));
            for (int i = tid; i < area; i += 256) {
                float v = vals[i];
                if (v > 0.0f) {
                    unsigned u = __float_as_uint(v);
                    if ((u & maskhi) == prefix)
                        atomicAdd(&hist[(u >> shift) & 255u], 1u);
                }
            }
            __syncthreads();
            if (tid == 0) {
                unsigned cum = 0;
                int bk = 255;
                for (; bk >= 0; --bk) {
                    unsigned c = hist[bk];
                    if (cum + c > r) break;
                    cum += c;
                }
                sb_bucket = bk;
                sb_r = (int)(r - cum);
            }
            __syncthreads();
            prefix |= ((unsigned)sb_bucket) << shift;
            r = (unsigned)sb_r;
        }
        thr = __uint_as_float(prefix);
    }

    if (tid == 0) {
        float* o = pairws + pair * PAIR_STRIDE;
        int* oi = (int*)o;
        o[0] = thr;
        o[1] = gcx; o[2] = gcy; o[3] = gbw; o[4] = gbh;
        o[5] = (*dmode != 0) ? ((gdiff >= 0.625f) ? 1.0f : 0.0f) : 1.0f;
        o[6] = 1.0f / sqrtf((float)dk);          // lam = dk^-0.5
        oi[7] = (int)gcls + 1;                   // class id
        oi[8] = wlo; oi[9] = whi; oi[10] = hlo; oi[11] = hhi;
        oi[12] = valid ? 1 : 0;
    }
}

// One thread per pixel: winner/tie/in-region over 64 boxes, write cls+pts.
__global__ __launch_bounds__(256) void pixel_kernel(const float* __restrict__ pred,
                                                    const float* __restrict__ pairws,
                                                    float* __restrict__ out_cls,
                                                    float* __restrict__ out_pts) {
    __shared__ float sb[NBOX][PAIR_STRIDE];
    const int b = blockIdx.y;
    const int tid = threadIdx.x;
    for (int i = tid; i < NBOX * PAIR_STRIDE; i += 256)
        ((float*)sb)[i] = pairws[b * NBOX * PAIR_STRIDE + i];
    __syncthreads();

    const int HW = IMG_H * IMG_W;
    int pix = blockIdx.x * 256 + tid;
    if (pix >= HW) return;
    int hh = pix / IMG_W;
    int ww = pix - hh * IMG_W;

    float cx, cy, pw, ph;
    decode_cell(pred, b, hh, ww, cx, cy, pw, ph);

    float best = 0.0f;
    int winner = -1, cnt = 0;
    bool inreg = false;
    for (int n = 0; n < NBOX; ++n) {
        const float* o = sb[n];
        const int* oi = (const int*)o;
        if (!oi[12]) continue;
        if (ww < oi[8] || ww > oi[9] || hh < oi[10] || hh > oi[11]) continue;
        inreg = true;
        float v = iou_one(cx, cy, pw, ph, o[1], o[2], o[3], o[4]);
        float kept = (v > o[0]) ? v : 0.0f;
        if (kept > best) { best = kept; winner = n; cnt = 1; }
        else if (kept == best && kept > 0.0f) { cnt++; }
    }

    bool assigned = best > 0.0f;
    float c0, c1, c2;
    if (assigned) {
        if (cnt > 1) { c0 = c1 = c2 = 0.0f; }
        else {
            int cid = ((const int*)sb[winner])[7];
            c0 = (cid == 0) ? 1.0f : 0.0f;
            c1 = (cid == 1) ? 1.0f : 0.0f;
            c2 = (cid == 2) ? 1.0f : 0.0f;
        }
    } else if (inreg) {
        c0 = c1 = c2 = 0.0f;
    } else {
        c0 = 1.0f; c1 = 0.0f; c2 = 0.0f;   // background one-hot
    }

    int cbase = (b * HW + pix) * 3;
    out_cls[cbase + 0] = c0;
    out_cls[cbase + 1] = c1;
    out_cls[cbase + 2] = c2;

    int pbase = (b * HW + pix) * 6;
    if (assigned) {
        const float* o = sb[winner];
        out_pts[pbase + 0] = o[1];
        out_pts[pbase + 1] = o[2];
        out_pts[pbase + 2] = o[3];
        out_pts[pbase + 3] = o[4];
        out_pts[pbase + 4] = o[5];
        out_pts[pbase + 5] = o[6];
    } else {
        out_pts[pbase + 0] = 1.0f;
        out_pts[pbase + 1] = 1.0f;
        out_pts[pbase + 2] = 1.0f;
        out_pts[pbase + 3] = 1.0f;
        out_pts[pbase + 4] = 1.0f;
        out_pts[pbase + 5] = 1.0f;
    }
}

extern "C" void kernel_launch(void* const* d_in, const int* in_sizes, int n_in,
                              void* d_out, int out_size, void* d_ws, size_t ws_size,
                              hipStream_t stream) {
    // inputs: feat (unused), pred (4,4,384,640), bboxes (4,64,6), difficult_mode (1)
    const float* pred = (const float*)d_in[1];
    const float* bboxes = (const float*)d_in[2];
    const int* dmode = (const int*)d_in[3];
    const int HW = IMG_H * IMG_W;
    float* out_cls = (float*)d_out;                       // (4,384,640,3)
    float* out_pts = (float*)d_out + (size_t)BS * HW * 3; // (4,384,640,6)
    float* pairws = (float*)d_ws;                         // 256 * 16 floats

    pair_kernel<<<dim3(BS * NBOX), dim3(256), 0, stream>>>(pred, bboxes, dmode, pairws);
    pixel_kernel<<<dim3((HW + 255) / 256, BS), dim3(256), 0, stream>>>(pred, pairws,
                                                                       out_cls, out_pts);
}

// Round 3
// 144.646 us; speedup vs baseline: 1.3211x; 1.3211x over previous
//
#include <hip/hip_runtime.h>

// Disable FMA contraction for the entire TU so IoU/decoding produce
// bitwise-identical results in both kernels (the top-dk selection uses
// strict > against the threshold, so bit-exactness matters).
#pragma clang fp contract(off)

#define IMG_W 640
#define IMG_H 384
#define NBOX 64
#define BS 4
#define PAIR_STRIDE 16
#define CAP 12544   // 112*112 >= worst-case region cells (<=103*103)
#define PAIR_TPB 1024
#define VPT 13      // 13*1024 = 13312 >= CAP

#define TILE_W 64
#define TILE_H 4
#define TILES_X (IMG_W / TILE_W)   // 10
#define TILES_Y (IMG_H / TILE_H)   // 96

// IoU exactly as reference _boxes_iou.
__device__ __forceinline__ float iou_one(float cx, float cy, float w, float h,
                                         float gcx, float gcy, float gw, float gh) {
    float b1minx = cx - w / 2.0f;
    float b1maxx = cx + w / 2.0f;
    float b1miny = cy - h / 2.0f;
    float b1maxy = cy + h / 2.0f;
    float b2minx = gcx - gw / 2.0f;
    float b2maxx = gcx + gw / 2.0f;
    float b2miny = gcy - gh / 2.0f;
    float b2maxy = gcy + gh / 2.0f;
    float iw = fmaxf(fminf(b1maxx, b2maxx) - fmaxf(b1minx, b2minx), 0.0f);
    float ih = fmaxf(fminf(b1maxy, b2maxy) - fmaxf(b1miny, b2miny), 0.0f);
    float inter = iw * ih;
    float uni = w * h + gw * gh - inter;
    uni = fmaxf(uni, 1e-6f);
    return inter / uni;
}

// Decode one cell exactly as reference _decode.
__device__ __forceinline__ void decode_cell(const float* __restrict__ pred, int b,
                                            int hh, int ww,
                                            float& cx, float& cy, float& w, float& h) {
    const int HW = IMG_H * IMG_W;
    int base = ((b * 4) * IMG_H + hh) * IMG_W + ww;
    float p0 = pred[base];
    float p1 = pred[base + HW];
    float p2 = pred[base + 2 * HW];
    float p3 = pred[base + 3 * HW];
    float rx = ((float)ww + 0.5f) * 2.0f;   // (w+0.5)*(MODEL_W/W) = *2.0
    float ry = ((float)hh + 0.5f) * 2.0f;
    float x1 = p0 * 80.0f + rx;
    float y1 = p1 * 80.0f + ry;
    float x2 = p2 * 80.0f + rx;
    float y2 = p3 * 80.0f + ry;
    w = x2 - x1;
    h = y2 - y1;
    cx = x1 + w / 2.0f;
    cy = y1 + h / 2.0f;
}

// One block (1024 thr) per (b, n) pair: region IoUs held in REGISTERS
// (<=13/thread), sum -> dk, exact 4-pass radix select of the rank-dk value,
// store 16-float descriptor.
__global__ __launch_bounds__(PAIR_TPB) void pair_kernel(const float* __restrict__ pred,
                                                        const float* __restrict__ bboxes,
                                                        const int* __restrict__ dmode,
                                                        float* __restrict__ pairws) {
    __shared__ unsigned hist[256];
    __shared__ float redf[PAIR_TPB / 64];
    __shared__ unsigned redu[PAIR_TPB / 64];
    __shared__ unsigned sb_bucket, sb_r;

    const int pair = blockIdx.x;
    const int b = pair >> 6;
    const int tid = threadIdx.x;

    const float* box = bboxes + pair * 6;
    float gx1 = box[0], gy1 = box[1], gx2 = box[2], gy2 = box[3];
    float gcls = box[4], gdiff = box[5];
    float gbw = gx2 - gx1;
    float gbh = gy2 - gy1;
    float gcx = gx1 + gbw / 2.0f;
    float gcy = gy1 + gbh / 2.0f;
    bool valid = (gbw * gbh) != 0.0f;

    // Region bounds, replicating reference float op order exactly.
    float mwf = floorf(fmaxf(gx1 * 640.0f / 1280.0f - 0.5f, 0.0f));
    float Mwf = ceilf(fminf(gx2 * 640.0f / 1280.0f - 0.5f, 639.0f));
    float mhf = floorf(fmaxf(gy1 * 384.0f / 768.0f - 0.5f, 0.0f));
    float Mhf = ceilf(fminf(gy2 * 384.0f / 768.0f - 0.5f, 383.0f));
    int wlo = (int)mwf, whi = (int)Mwf, hlo = (int)mhf, hhi = (int)Mhf;
    int rw = whi - wlo + 1;
    int rh = hhi - hlo + 1;
    int area = (valid && rw > 0 && rh > 0) ? rw * rh : 0;
    if (area > CAP) area = CAP;   // cannot trigger for harness inputs (<=10609)

    float v[VPT];
    float lsum = 0.0f;
    unsigned lpos = 0;
#pragma unroll
    for (int k = 0; k < VPT; ++k) {
        int i = tid + k * PAIR_TPB;
        float val = 0.0f;
        if (i < area) {
            int hh = hlo + i / rw;
            int ww = wlo + i % rw;
            float cx, cy, pw, ph;
            decode_cell(pred, b, hh, ww, cx, cy, pw, ph);
            val = iou_one(cx, cy, pw, ph, gcx, gcy, gbw, gbh);
        }
        v[k] = val;
        lsum += val;
        lpos += (val > 0.0f) ? 1u : 0u;
    }
    // wave reduce (64 lanes) then cross-wave via LDS
    for (int off = 32; off > 0; off >>= 1) {
        lsum += __shfl_down(lsum, off, 64);
        lpos += __shfl_down(lpos, off, 64);
    }
    int wave = tid >> 6;
    if ((tid & 63) == 0) { redf[wave] = lsum; redu[wave] = lpos; }
    __syncthreads();
    if (tid == 0) {
        float s = 0.0f; unsigned p = 0;
        for (int i = 0; i < PAIR_TPB / 64; ++i) { s += redf[i]; p += redu[i]; }
        redf[0] = s; redu[0] = p;
    }
    __syncthreads();
    float sum = redf[0];
    unsigned npos = redu[0];
    int dk = (int)ceilf(fmaxf(sum, 1.0f));

    // Exact threshold: rank-dk (0-indexed desc) over full H*W array = positives
    // then zeros. If dk >= npos the threshold is 0.
    float thr = 0.0f;
    if ((unsigned)dk < npos) {
        unsigned prefix = 0;
        unsigned r = (unsigned)dk;
        for (int shift = 24; shift >= 0; shift -= 8) {
            if (tid < 256) hist[tid] = 0;
            __syncthreads();
            unsigned maskhi = (shift == 24) ? 0u : (0xFFFFFFFFu << (shift + 8));
#pragma unroll
            for (int k = 0; k < VPT; ++k) {
                float val = v[k];
                if (val > 0.0f) {
                    unsigned u = __float_as_uint(val);
                    if ((u & maskhi) == prefix)
                        atomicAdd(&hist[(u >> shift) & 255u], 1u);
                }
            }
            __syncthreads();
            if (tid == 0) {
                unsigned cum = 0;
                int bk = 255;
                for (; bk >= 0; --bk) {
                    unsigned c = hist[bk];
                    if (cum + c > r) break;
                    cum += c;
                }
                sb_bucket = (unsigned)bk;
                sb_r = r - cum;
            }
            __syncthreads();
            prefix |= sb_bucket << shift;
            r = sb_r;
            __syncthreads();   // protect hist reuse next pass
        }
        thr = __uint_as_float(prefix);
    }

    if (tid == 0) {
        float* o = pairws + pair * PAIR_STRIDE;
        int* oi = (int*)o;
        o[0] = thr;
        o[1] = gcx; o[2] = gcy; o[3] = gbw; o[4] = gbh;
        o[5] = (*dmode != 0) ? ((gdiff >= 0.625f) ? 1.0f : 0.0f) : 1.0f;
        o[6] = 1.0f / sqrtf((float)dk);          // lam = dk^-0.5
        oi[7] = (int)gcls + 1;                   // class id
        oi[8] = wlo; oi[9] = whi; oi[10] = hlo; oi[11] = hhi;
        oi[12] = valid ? 1 : 0;
    }
}

// One block per 64x4 pixel tile: wave-0 prunes the 64 boxes against the tile
// rect into a compacted LDS list (order-preserving -> argmax semantics kept),
// then each thread resolves its pixel over the short active list.
__global__ __launch_bounds__(256) void pixel_kernel(const float* __restrict__ pred,
                                                    const float* __restrict__ pairws,
                                                    float* __restrict__ out_cls,
                                                    float* __restrict__ out_pts) {
    __shared__ float sb[NBOX][PAIR_STRIDE];
    __shared__ int list[NBOX];
    __shared__ int nact_s;

    const int b = blockIdx.y;
    const int tid = threadIdx.x;
    for (int i = tid; i < NBOX * PAIR_STRIDE; i += 256)
        ((float*)sb)[i] = pairws[b * NBOX * PAIR_STRIDE + i];
    __syncthreads();

    const int tilex = blockIdx.x % TILES_X;
    const int tiley = blockIdx.x / TILES_X;
    const int tw0 = tilex * TILE_W, tw1 = tw0 + TILE_W - 1;
    const int th0 = tiley * TILE_H, th1 = th0 + TILE_H - 1;

    // wave 0: prune + compact
    if (tid < 64) {
        const int* oi = (const int*)sb[tid];
        bool ok = oi[12] && oi[9] >= tw0 && oi[8] <= tw1 && oi[11] >= th0 && oi[10] <= th1;
        unsigned long long mask = __ballot(ok);
        if (ok) {
            int pos = __popcll(mask & ((1ull << tid) - 1ull));
            list[pos] = tid;
        }
        if (tid == 0) nact_s = __popcll(mask);
    }
    __syncthreads();
    const int nact = nact_s;

    const int ww = tw0 + (tid & (TILE_W - 1));
    const int hh = th0 + (tid >> 6);

    float cx, cy, pw, ph;
    decode_cell(pred, b, hh, ww, cx, cy, pw, ph);

    float best = 0.0f;
    int winner = -1, cnt = 0;
    bool inreg = false;
    for (int j = 0; j < nact; ++j) {
        int n = list[j];
        const float* o = sb[n];
        const int* oi = (const int*)o;
        if (ww < oi[8] || ww > oi[9] || hh < oi[10] || hh > oi[11]) continue;
        inreg = true;
        float v = iou_one(cx, cy, pw, ph, o[1], o[2], o[3], o[4]);
        float kept = (v > o[0]) ? v : 0.0f;
        if (kept > best) { best = kept; winner = n; cnt = 1; }
        else if (kept == best && kept > 0.0f) { cnt++; }
    }

    bool assigned = best > 0.0f;
    float c0, c1, c2;
    if (assigned) {
        if (cnt > 1) { c0 = c1 = c2 = 0.0f; }
        else {
            int cid = ((const int*)sb[winner])[7];
            c0 = (cid == 0) ? 1.0f : 0.0f;
            c1 = (cid == 1) ? 1.0f : 0.0f;
            c2 = (cid == 2) ? 1.0f : 0.0f;
        }
    } else if (inreg) {
        c0 = c1 = c2 = 0.0f;
    } else {
        c0 = 1.0f; c1 = 0.0f; c2 = 0.0f;   // background one-hot
    }

    const int HW = IMG_H * IMG_W;
    int pix = hh * IMG_W + ww;
    int cbase = (b * HW + pix) * 3;
    out_cls[cbase + 0] = c0;
    out_cls[cbase + 1] = c1;
    out_cls[cbase + 2] = c2;

    int pbase = (b * HW + pix) * 6;
    if (assigned) {
        const float* o = sb[winner];
        out_pts[pbase + 0] = o[1];
        out_pts[pbase + 1] = o[2];
        out_pts[pbase + 2] = o[3];
        out_pts[pbase + 3] = o[4];
        out_pts[pbase + 4] = o[5];
        out_pts[pbase + 5] = o[6];
    } else {
        out_pts[pbase + 0] = 1.0f;
        out_pts[pbase + 1] = 1.0f;
        out_pts[pbase + 2] = 1.0f;
        out_pts[pbase + 3] = 1.0f;
        out_pts[pbase + 4] = 1.0f;
        out_pts[pbase + 5] = 1.0f;
    }
}

extern "C" void kernel_launch(void* const* d_in, const int* in_sizes, int n_in,
                              void* d_out, int out_size, void* d_ws, size_t ws_size,
                              hipStream_t stream) {
    // inputs: feat (unused), pred (4,4,384,640), bboxes (4,64,6), difficult_mode (1)
    const float* pred = (const float*)d_in[1];
    const float* bboxes = (const float*)d_in[2];
    const int* dmode = (const int*)d_in[3];
    const int HW = IMG_H * IMG_W;
    float* out_cls = (float*)d_out;                       // (4,384,640,3)
    float* out_pts = (float*)d_out + (size_t)BS * HW * 3; // (4,384,640,6)
    float* pairws = (float*)d_ws;                         // 256 * 16 floats

    pair_kernel<<<dim3(BS * NBOX), dim3(PAIR_TPB), 0, stream>>>(pred, bboxes, dmode, pairws);
    pixel_kernel<<<dim3(TILES_X * TILES_Y, BS), dim3(256), 0, stream>>>(pred, pairws,
                                                                        out_cls, out_pts);
}

// Round 4
// 112.992 us; speedup vs baseline: 1.6911x; 1.2801x over previous
//
#include <hip/hip_runtime.h>

// Disable FMA contraction for the entire TU so IoU/decoding produce
// bitwise-identical results in both kernels (the top-dk selection uses
// strict > against the threshold, so bit-exactness matters).
#pragma clang fp contract(off)

#define IMG_W 640
#define IMG_H 384
#define NBOX 64
#define BS 4
#define PAIR_STRIDE 16
#define CAP 12544   // 112*112 >= worst-case region cells (<=103*103)
#define PAIR_TPB 1024
#define NHIST 8     // sub-histograms to spread LDS atomic contention

#define TILE_W 64
#define TILE_H 4
#define TILES_X (IMG_W / TILE_W)   // 10
#define TILES_Y (IMG_H / TILE_H)   // 96

// IoU exactly as reference _boxes_iou.
__device__ __forceinline__ float iou_one(float cx, float cy, float w, float h,
                                         float gcx, float gcy, float gw, float gh) {
    float b1minx = cx - w / 2.0f;
    float b1maxx = cx + w / 2.0f;
    float b1miny = cy - h / 2.0f;
    float b1maxy = cy + h / 2.0f;
    float b2minx = gcx - gw / 2.0f;
    float b2maxx = gcx + gw / 2.0f;
    float b2miny = gcy - gh / 2.0f;
    float b2maxy = gcy + gh / 2.0f;
    float iw = fmaxf(fminf(b1maxx, b2maxx) - fmaxf(b1minx, b2minx), 0.0f);
    float ih = fmaxf(fminf(b1maxy, b2maxy) - fmaxf(b1miny, b2miny), 0.0f);
    float inter = iw * ih;
    float uni = w * h + gw * gh - inter;
    uni = fmaxf(uni, 1e-6f);
    return inter / uni;
}

// Decode one cell exactly as reference _decode.
__device__ __forceinline__ void decode_cell(const float* __restrict__ pred, int b,
                                            int hh, int ww,
                                            float& cx, float& cy, float& w, float& h) {
    const int HW = IMG_H * IMG_W;
    int base = ((b * 4) * IMG_H + hh) * IMG_W + ww;
    float p0 = pred[base];
    float p1 = pred[base + HW];
    float p2 = pred[base + 2 * HW];
    float p3 = pred[base + 3 * HW];
    float rx = ((float)ww + 0.5f) * 2.0f;   // (w+0.5)*(MODEL_W/W) = *2.0
    float ry = ((float)hh + 0.5f) * 2.0f;
    float x1 = p0 * 80.0f + rx;
    float y1 = p1 * 80.0f + ry;
    float x2 = p2 * 80.0f + rx;
    float y2 = p3 * 80.0f + ry;
    w = x2 - x1;
    h = y2 - y1;
    cx = x1 + w / 2.0f;
    cy = y1 + h / 2.0f;
}

// One block (1024 thr) per (b, n) pair: region IoUs in LDS, sum -> dk, exact
// 4-pass radix select with PARALLEL histogram rank-find (the R3 version's
// tid==0 serial scan was ~123k cycles of single-outstanding LDS latency).
__global__ __launch_bounds__(PAIR_TPB) void pair_kernel(const float* __restrict__ pred,
                                                        const float* __restrict__ bboxes,
                                                        const int* __restrict__ dmode,
                                                        float* __restrict__ pairws) {
    __shared__ float vals[CAP];                 // 50176 B
    __shared__ unsigned hist[NHIST][256];       // 8192 B
    __shared__ float redf[PAIR_TPB / 64];
    __shared__ unsigned redu[PAIR_TPB / 64];
    __shared__ unsigned wsum[4];
    __shared__ unsigned sb_bucket, sb_r;

    const int pair = blockIdx.x;
    const int b = pair >> 6;
    const int tid = threadIdx.x;

    const float* box = bboxes + pair * 6;
    float gx1 = box[0], gy1 = box[1], gx2 = box[2], gy2 = box[3];
    float gcls = box[4], gdiff = box[5];
    float gbw = gx2 - gx1;
    float gbh = gy2 - gy1;
    float gcx = gx1 + gbw / 2.0f;
    float gcy = gy1 + gbh / 2.0f;
    bool valid = (gbw * gbh) != 0.0f;

    // Region bounds, replicating reference float op order exactly.
    float mwf = floorf(fmaxf(gx1 * 640.0f / 1280.0f - 0.5f, 0.0f));
    float Mwf = ceilf(fminf(gx2 * 640.0f / 1280.0f - 0.5f, 639.0f));
    float mhf = floorf(fmaxf(gy1 * 384.0f / 768.0f - 0.5f, 0.0f));
    float Mhf = ceilf(fminf(gy2 * 384.0f / 768.0f - 0.5f, 383.0f));
    int wlo = (int)mwf, whi = (int)Mwf, hlo = (int)mhf, hhi = (int)Mhf;
    int rw = whi - wlo + 1;
    int rh = hhi - hlo + 1;
    int area = (valid && rw > 0 && rh > 0) ? rw * rh : 0;
    if (area > CAP) area = CAP;   // cannot trigger for harness inputs (<=10609)

    float lsum = 0.0f;
    unsigned lpos = 0;
    for (int i = tid; i < area; i += PAIR_TPB) {
        int hh = hlo + i / rw;
        int ww = wlo + i % rw;
        float cx, cy, pw, ph;
        decode_cell(pred, b, hh, ww, cx, cy, pw, ph);
        float val = iou_one(cx, cy, pw, ph, gcx, gcy, gbw, gbh);
        vals[i] = val;
        lsum += val;
        lpos += (val > 0.0f) ? 1u : 0u;
    }
    // wave reduce (64 lanes) then wave-0 combines the 16 wave partials
    for (int off = 32; off > 0; off >>= 1) {
        lsum += __shfl_down(lsum, off, 64);
        lpos += __shfl_down(lpos, off, 64);
    }
    int wave = tid >> 6;
    if ((tid & 63) == 0) { redf[wave] = lsum; redu[wave] = lpos; }
    __syncthreads();
    if (tid < 64) {
        float s = (tid < PAIR_TPB / 64) ? redf[tid] : 0.0f;
        unsigned p = (tid < PAIR_TPB / 64) ? redu[tid] : 0u;
        for (int off = 8; off > 0; off >>= 1) {
            s += __shfl_down(s, off, 64);
            p += __shfl_down(p, off, 64);
        }
        if (tid == 0) { redf[0] = s; redu[0] = p; }
    }
    __syncthreads();
    float sum = redf[0];
    unsigned npos = redu[0];
    int dk = (int)ceilf(fmaxf(sum, 1.0f));

    // Exact threshold: rank-dk (0-indexed desc) over full H*W array = positives
    // then zeros. If dk >= npos the threshold is 0.
    float thr = 0.0f;
    if ((unsigned)dk < npos) {
        unsigned prefix = 0;
        unsigned r = (unsigned)dk;
        for (int shift = 24; shift >= 0; shift -= 8) {
            // zero the 8 sub-histograms (2048 words, 1024 threads)
            ((unsigned*)hist)[tid] = 0;
            ((unsigned*)hist)[tid + PAIR_TPB] = 0;
            __syncthreads();
            unsigned maskhi = (shift == 24) ? 0u : (0xFFFFFFFFu << (shift + 8));
            unsigned* myhist = hist[(tid >> 7) & (NHIST - 1)];
            for (int i = tid; i < area; i += PAIR_TPB) {
                float val = vals[i];
                if (val > 0.0f) {
                    unsigned u = __float_as_uint(val);
                    if ((u & maskhi) == prefix)
                        atomicAdd(&myhist[(u >> shift) & 255u], 1u);
                }
            }
            __syncthreads();
            // Parallel rank-find: thread t (<256) owns bucket 255-t so
            // ascending t == descending value order. Reversed prefix sum via
            // wave scan + 4-wave combine, then locate the bucket containing r.
            unsigned c = 0, incl = 0;
            if (tid < 256) {
                int bk = 255 - tid;
#pragma unroll
                for (int j = 0; j < NHIST; ++j) c += hist[j][bk];
                incl = c;
                for (int off = 1; off < 64; off <<= 1) {
                    unsigned y = __shfl_up(incl, off, 64);
                    if ((tid & 63) >= off) incl += y;
                }
                if ((tid & 63) == 63) wsum[tid >> 6] = incl;
            }
            __syncthreads();
            if (tid < 256) {
                unsigned pre = 0;
                int w = tid >> 6;
                for (int j = 0; j < w; ++j) pre += wsum[j];
                incl += pre;
                unsigned excl = incl - c;
                if (r >= excl && r < incl) {   // exactly one thread matches
                    sb_bucket = (unsigned)(255 - tid);
                    sb_r = r - excl;
                }
            }
            __syncthreads();
            prefix |= sb_bucket << shift;
            r = sb_r;
            __syncthreads();   // protect hist/wsum reuse next pass
        }
        thr = __uint_as_float(prefix);
    }

    if (tid == 0) {
        float* o = pairws + pair * PAIR_STRIDE;
        int* oi = (int*)o;
        o[0] = thr;
        o[1] = gcx; o[2] = gcy; o[3] = gbw; o[4] = gbh;
        o[5] = (*dmode != 0) ? ((gdiff >= 0.625f) ? 1.0f : 0.0f) : 1.0f;
        o[6] = 1.0f / sqrtf((float)dk);          // lam = dk^-0.5
        oi[7] = (int)gcls + 1;                   // class id
        oi[8] = wlo; oi[9] = whi; oi[10] = hlo; oi[11] = hhi;
        oi[12] = valid ? 1 : 0;
    }
}

// One block per 64x4 pixel tile: wave-0 prunes the 64 boxes against the tile
// rect into a compacted LDS list (order-preserving -> argmax semantics kept),
// then each thread resolves its pixel over the short active list.
__global__ __launch_bounds__(256) void pixel_kernel(const float* __restrict__ pred,
                                                    const float* __restrict__ pairws,
                                                    float* __restrict__ out_cls,
                                                    float* __restrict__ out_pts) {
    __shared__ float sb[NBOX][PAIR_STRIDE];
    __shared__ int list[NBOX];
    __shared__ int nact_s;

    const int b = blockIdx.y;
    const int tid = threadIdx.x;
    for (int i = tid; i < NBOX * PAIR_STRIDE; i += 256)
        ((float*)sb)[i] = pairws[b * NBOX * PAIR_STRIDE + i];
    __syncthreads();

    const int tilex = blockIdx.x % TILES_X;
    const int tiley = blockIdx.x / TILES_X;
    const int tw0 = tilex * TILE_W, tw1 = tw0 + TILE_W - 1;
    const int th0 = tiley * TILE_H, th1 = th0 + TILE_H - 1;

    // wave 0: prune + compact
    if (tid < 64) {
        const int* oi = (const int*)sb[tid];
        bool ok = oi[12] && oi[9] >= tw0 && oi[8] <= tw1 && oi[11] >= th0 && oi[10] <= th1;
        unsigned long long mask = __ballot(ok);
        if (ok) {
            int pos = __popcll(mask & ((1ull << tid) - 1ull));
            list[pos] = tid;
        }
        if (tid == 0) nact_s = __popcll(mask);
    }
    __syncthreads();
    const int nact = nact_s;

    const int ww = tw0 + (tid & (TILE_W - 1));
    const int hh = th0 + (tid >> 6);

    float cx, cy, pw, ph;
    decode_cell(pred, b, hh, ww, cx, cy, pw, ph);

    float best = 0.0f;
    int winner = -1, cnt = 0;
    bool inreg = false;
    for (int j = 0; j < nact; ++j) {
        int n = list[j];
        const float* o = sb[n];
        const int* oi = (const int*)o;
        if (ww < oi[8] || ww > oi[9] || hh < oi[10] || hh > oi[11]) continue;
        inreg = true;
        float v = iou_one(cx, cy, pw, ph, o[1], o[2], o[3], o[4]);
        float kept = (v > o[0]) ? v : 0.0f;
        if (kept > best) { best = kept; winner = n; cnt = 1; }
        else if (kept == best && kept > 0.0f) { cnt++; }
    }

    bool assigned = best > 0.0f;
    float c0, c1, c2;
    if (assigned) {
        if (cnt > 1) { c0 = c1 = c2 = 0.0f; }
        else {
            int cid = ((const int*)sb[winner])[7];
            c0 = (cid == 0) ? 1.0f : 0.0f;
            c1 = (cid == 1) ? 1.0f : 0.0f;
            c2 = (cid == 2) ? 1.0f : 0.0f;
        }
    } else if (inreg) {
        c0 = c1 = c2 = 0.0f;
    } else {
        c0 = 1.0f; c1 = 0.0f; c2 = 0.0f;   // background one-hot
    }

    const int HW = IMG_H * IMG_W;
    int pix = hh * IMG_W + ww;
    int cbase = (b * HW + pix) * 3;
    out_cls[cbase + 0] = c0;
    out_cls[cbase + 1] = c1;
    out_cls[cbase + 2] = c2;

    int pbase = (b * HW + pix) * 6;
    if (assigned) {
        const float* o = sb[winner];
        out_pts[pbase + 0] = o[1];
        out_pts[pbase + 1] = o[2];
        out_pts[pbase + 2] = o[3];
        out_pts[pbase + 3] = o[4];
        out_pts[pbase + 4] = o[5];
        out_pts[pbase + 5] = o[6];
    } else {
        out_pts[pbase + 0] = 1.0f;
        out_pts[pbase + 1] = 1.0f;
        out_pts[pbase + 2] = 1.0f;
        out_pts[pbase + 3] = 1.0f;
        out_pts[pbase + 4] = 1.0f;
        out_pts[pbase + 5] = 1.0f;
    }
}

extern "C" void kernel_launch(void* const* d_in, const int* in_sizes, int n_in,
                              void* d_out, int out_size, void* d_ws, size_t ws_size,
                              hipStream_t stream) {
    // inputs: feat (unused), pred (4,4,384,640), bboxes (4,64,6), difficult_mode (1)
    const float* pred = (const float*)d_in[1];
    const float* bboxes = (const float*)d_in[2];
    const int* dmode = (const int*)d_in[3];
    const int HW = IMG_H * IMG_W;
    float* out_cls = (float*)d_out;                       // (4,384,640,3)
    float* out_pts = (float*)d_out + (size_t)BS * HW * 3; // (4,384,640,6)
    float* pairws = (float*)d_ws;                         // 256 * 16 floats

    pair_kernel<<<dim3(BS * NBOX), dim3(PAIR_TPB), 0, stream>>>(pred, bboxes, dmode, pairws);
    pixel_kernel<<<dim3(TILES_X * TILES_Y, BS), dim3(256), 0, stream>>>(pred, pairws,
                                                                        out_cls, out_pts);
}

// Round 5
// 109.231 us; speedup vs baseline: 1.7494x; 1.0344x over previous
//
#include <hip/hip_runtime.h>

// Disable FMA contraction for the entire TU so IoU/decoding produce
// bitwise-identical results in both kernels (the top-dk selection uses
// strict > against the threshold, so bit-exactness matters).
#pragma clang fp contract(off)

#define IMG_W 640
#define IMG_H 384
#define NBOX 64
#define BS 4
#define PAIR_STRIDE 16
#define CAP 12544   // 112*112 >= worst-case region cells (<=103*103)
#define PAIR_TPB 1024
#define NHIST 8     // sub-histograms to spread LDS atomic contention

#define TILE_W 64
#define TILE_H 4
#define TILES_X (IMG_W / TILE_W)   // 10
#define TILES_Y (IMG_H / TILE_H)   // 96

// IoU exactly as reference _boxes_iou.
__device__ __forceinline__ float iou_one(float cx, float cy, float w, float h,
                                         float gcx, float gcy, float gw, float gh) {
    float b1minx = cx - w / 2.0f;
    float b1maxx = cx + w / 2.0f;
    float b1miny = cy - h / 2.0f;
    float b1maxy = cy + h / 2.0f;
    float b2minx = gcx - gw / 2.0f;
    float b2maxx = gcx + gw / 2.0f;
    float b2miny = gcy - gh / 2.0f;
    float b2maxy = gcy + gh / 2.0f;
    float iw = fmaxf(fminf(b1maxx, b2maxx) - fmaxf(b1minx, b2minx), 0.0f);
    float ih = fmaxf(fminf(b1maxy, b2maxy) - fmaxf(b1miny, b2miny), 0.0f);
    float inter = iw * ih;
    float uni = w * h + gw * gh - inter;
    uni = fmaxf(uni, 1e-6f);
    return inter / uni;
}

// Decode one cell exactly as reference _decode.
__device__ __forceinline__ void decode_cell(const float* __restrict__ pred, int b,
                                            int hh, int ww,
                                            float& cx, float& cy, float& w, float& h) {
    const int HW = IMG_H * IMG_W;
    int base = ((b * 4) * IMG_H + hh) * IMG_W + ww;
    float p0 = pred[base];
    float p1 = pred[base + HW];
    float p2 = pred[base + 2 * HW];
    float p3 = pred[base + 3 * HW];
    float rx = ((float)ww + 0.5f) * 2.0f;   // (w+0.5)*(MODEL_W/W) = *2.0
    float ry = ((float)hh + 0.5f) * 2.0f;
    float x1 = p0 * 80.0f + rx;
    float y1 = p1 * 80.0f + ry;
    float x2 = p2 * 80.0f + rx;
    float y2 = p3 * 80.0f + ry;
    w = x2 - x1;
    h = y2 - y1;
    cx = x1 + w / 2.0f;
    cy = y1 + h / 2.0f;
}

// One block (1024 thr) per (b, n) pair: region IoUs in LDS, sum -> dk, exact
// radix select with parallel histogram rank-find, EARLY-EXIT to a direct
// gather-select once the surviving candidate set is <= 64 (typical after
// 2 of 4 passes, since IoUs cluster into ~5 exponent buckets).
__global__ __launch_bounds__(PAIR_TPB) void pair_kernel(const float* __restrict__ pred,
                                                        const float* __restrict__ bboxes,
                                                        const int* __restrict__ dmode,
                                                        float* __restrict__ pairws) {
    __shared__ float vals[CAP];                 // 50176 B
    __shared__ unsigned hist[NHIST][256];       // 8192 B
    __shared__ float redf[PAIR_TPB / 64];
    __shared__ unsigned redu[PAIR_TPB / 64];
    __shared__ unsigned wsum[4];
    __shared__ unsigned sb_bucket, sb_r, sb_cnt;
    __shared__ float cand[64];
    __shared__ unsigned cand_n;
    __shared__ float sthr;

    const int pair = blockIdx.x;
    const int b = pair >> 6;
    const int tid = threadIdx.x;

    const float* box = bboxes + pair * 6;
    float gx1 = box[0], gy1 = box[1], gx2 = box[2], gy2 = box[3];
    float gcls = box[4], gdiff = box[5];
    float gbw = gx2 - gx1;
    float gbh = gy2 - gy1;
    float gcx = gx1 + gbw / 2.0f;
    float gcy = gy1 + gbh / 2.0f;
    bool valid = (gbw * gbh) != 0.0f;

    // Region bounds, replicating reference float op order exactly.
    float mwf = floorf(fmaxf(gx1 * 640.0f / 1280.0f - 0.5f, 0.0f));
    float Mwf = ceilf(fminf(gx2 * 640.0f / 1280.0f - 0.5f, 639.0f));
    float mhf = floorf(fmaxf(gy1 * 384.0f / 768.0f - 0.5f, 0.0f));
    float Mhf = ceilf(fminf(gy2 * 384.0f / 768.0f - 0.5f, 383.0f));
    int wlo = (int)mwf, whi = (int)Mwf, hlo = (int)mhf, hhi = (int)Mhf;
    int rw = whi - wlo + 1;
    int rh = hhi - hlo + 1;
    int area = (valid && rw > 0 && rh > 0) ? rw * rh : 0;
    if (area > CAP) area = CAP;   // cannot trigger for harness inputs (<=10609)

    // Magic-number division for i/rw (exact: rw<=2^7, i<2^32, err < i/2^32 < 1)
    unsigned inv_rw = (rw > 1) ? (0xFFFFFFFFu / (unsigned)rw + 1u) : 0u;

    float lsum = 0.0f;
    unsigned lpos = 0;
    for (int i = tid; i < area; i += PAIR_TPB) {
        int q = (rw > 1) ? (int)(((unsigned long long)(unsigned)i * inv_rw) >> 32) : i;
        int hh = hlo + q;
        int ww = wlo + (i - q * rw);
        float cx, cy, pw, ph;
        decode_cell(pred, b, hh, ww, cx, cy, pw, ph);
        float val = iou_one(cx, cy, pw, ph, gcx, gcy, gbw, gbh);
        vals[i] = val;
        lsum += val;
        lpos += (val > 0.0f) ? 1u : 0u;
    }
    // wave reduce (64 lanes) then wave-0 combines the 16 wave partials
    for (int off = 32; off > 0; off >>= 1) {
        lsum += __shfl_down(lsum, off, 64);
        lpos += __shfl_down(lpos, off, 64);
    }
    int wave = tid >> 6;
    if ((tid & 63) == 0) { redf[wave] = lsum; redu[wave] = lpos; }
    __syncthreads();
    if (tid < 64) {
        float s = (tid < PAIR_TPB / 64) ? redf[tid] : 0.0f;
        unsigned p = (tid < PAIR_TPB / 64) ? redu[tid] : 0u;
        for (int off = 8; off > 0; off >>= 1) {
            s += __shfl_down(s, off, 64);
            p += __shfl_down(p, off, 64);
        }
        if (tid == 0) { redf[0] = s; redu[0] = p; }
    }
    __syncthreads();
    float sum = redf[0];
    unsigned npos = redu[0];
    int dk = (int)ceilf(fmaxf(sum, 1.0f));

    // Exact threshold: rank-dk (0-indexed desc) over full H*W array = positives
    // then zeros. If dk >= npos the threshold is 0.
    float thr = 0.0f;
    if ((unsigned)dk < npos) {
        unsigned prefix = 0;
        unsigned r = (unsigned)dk;
        unsigned cnt = npos;
        bool done = false;
        for (int shift = 24; shift >= 0; shift -= 8) {
            unsigned maskhi = (shift == 24) ? 0u : (0xFFFFFFFFu << (shift + 8));
            if (cnt <= 64u) {
                // Gather the <=64 candidates matching prefix, rank-select direct.
                if (tid == 0) cand_n = 0;
                __syncthreads();
                for (int i = tid; i < area; i += PAIR_TPB) {
                    float val = vals[i];
                    if (val > 0.0f) {
                        unsigned u = __float_as_uint(val);
                        if ((u & maskhi) == prefix) {
                            unsigned p = atomicAdd(&cand_n, 1u);
                            cand[p] = val;
                        }
                    }
                }
                __syncthreads();
                if (tid < 64) {
                    unsigned c = cand_n;
                    if (tid < c) {
                        float mv = cand[tid];
                        unsigned g = 0, e = 0;
                        for (unsigned j = 0; j < c; ++j) {
                            float o = cand[j];
                            g += (o > mv) ? 1u : 0u;
                            e += (o == mv) ? 1u : 0u;
                        }
                        if (g <= r && r < g + e) sthr = mv;  // all matchers equal
                    }
                }
                __syncthreads();
                thr = sthr;
                done = true;
                break;
            }
            // zero the 8 sub-histograms (2048 words, 1024 threads)
            ((unsigned*)hist)[tid] = 0;
            ((unsigned*)hist)[tid + PAIR_TPB] = 0;
            __syncthreads();
            unsigned* myhist = hist[(tid >> 7) & (NHIST - 1)];
            for (int i = tid; i < area; i += PAIR_TPB) {
                float val = vals[i];
                if (val > 0.0f) {
                    unsigned u = __float_as_uint(val);
                    if ((u & maskhi) == prefix)
                        atomicAdd(&myhist[(u >> shift) & 255u], 1u);
                }
            }
            __syncthreads();
            // Parallel rank-find: thread t (<256) owns bucket 255-t so
            // ascending t == descending value order. Reversed prefix sum via
            // wave scan + 4-wave combine, then locate the bucket containing r.
            unsigned c = 0, incl = 0;
            if (tid < 256) {
                int bk = 255 - tid;
#pragma unroll
                for (int j = 0; j < NHIST; ++j) c += hist[j][bk];
                incl = c;
                for (int off = 1; off < 64; off <<= 1) {
                    unsigned y = __shfl_up(incl, off, 64);
                    if ((tid & 63) >= off) incl += y;
                }
                if ((tid & 63) == 63) wsum[tid >> 6] = incl;
            }
            __syncthreads();
            if (tid < 256) {
                unsigned pre = 0;
                int w = tid >> 6;
                for (int j = 0; j < w; ++j) pre += wsum[j];
                incl += pre;
                unsigned excl = incl - c;
                if (r >= excl && r < incl) {   // exactly one thread matches
                    sb_bucket = (unsigned)(255 - tid);
                    sb_r = r - excl;
                    sb_cnt = c;
                }
            }
            __syncthreads();
            prefix |= sb_bucket << shift;
            r = sb_r;
            cnt = sb_cnt;
            __syncthreads();   // protect hist/wsum reuse next pass
        }
        // If all 4 passes ran without an early exit, the full 32-bit prefix
        // IS the rank value (cnt>64 identical duplicates).
        if (!done) thr = __uint_as_float(prefix);
    }

    if (tid == 0) {
        float* o = pairws + pair * PAIR_STRIDE;
        int* oi = (int*)o;
        o[0] = thr;
        o[1] = gcx; o[2] = gcy; o[3] = gbw; o[4] = gbh;
        o[5] = (*dmode != 0) ? ((gdiff >= 0.625f) ? 1.0f : 0.0f) : 1.0f;
        o[6] = 1.0f / sqrtf((float)dk);          // lam = dk^-0.5
        oi[7] = (int)gcls + 1;                   // class id
        oi[8] = wlo; oi[9] = whi; oi[10] = hlo; oi[11] = hhi;
        oi[12] = valid ? 1 : 0;
    }
}

// One block per 64x4 pixel tile: wave-0 prunes the 64 boxes against the tile
// rect into a compacted LDS list (order-preserving -> argmax semantics kept),
// each thread resolves its pixel over the short active list, then outputs are
// staged in LDS and written as fully-coalesced float4s.
__global__ __launch_bounds__(256) void pixel_kernel(const float* __restrict__ pred,
                                                    const float* __restrict__ pairws,
                                                    float* __restrict__ out_cls,
                                                    float* __restrict__ out_pts) {
    __shared__ __align__(16) float sb[NBOX][PAIR_STRIDE];        // 4 KB
    __shared__ int list[NBOX];
    __shared__ int nact_s;
    __shared__ __align__(16) float scls[TILE_H][TILE_W * 3];     // 3 KB
    __shared__ __align__(16) float spts[TILE_H][TILE_W * 6];     // 6 KB

    const int b = blockIdx.y;
    const int tid = threadIdx.x;
    ((float4*)sb)[tid] = ((const float4*)(pairws + b * NBOX * PAIR_STRIDE))[tid];
    __syncthreads();

    const int tilex = blockIdx.x % TILES_X;
    const int tiley = blockIdx.x / TILES_X;
    const int tw0 = tilex * TILE_W, tw1 = tw0 + TILE_W - 1;
    const int th0 = tiley * TILE_H, th1 = th0 + TILE_H - 1;

    // wave 0: prune + compact
    if (tid < 64) {
        const int* oi = (const int*)sb[tid];
        bool ok = oi[12] && oi[9] >= tw0 && oi[8] <= tw1 && oi[11] >= th0 && oi[10] <= th1;
        unsigned long long mask = __ballot(ok);
        if (ok) {
            int pos = __popcll(mask & ((1ull << tid) - 1ull));
            list[pos] = tid;
        }
        if (tid == 0) nact_s = __popcll(mask);
    }
    __syncthreads();
    const int nact = nact_s;

    const int col = tid & (TILE_W - 1);
    const int row = tid >> 6;                  // 0..3
    const int ww = tw0 + col;
    const int hh = th0 + row;

    float c0, c1, c2, p0, p1, p2, p3, p4, p5;
    if (nact == 0) {
        // whole tile is background: no pred read, no IoU
        c0 = 1.0f; c1 = 0.0f; c2 = 0.0f;
        p0 = p1 = p2 = p3 = p4 = p5 = 1.0f;
    } else {
        float cx, cy, pw, ph;
        decode_cell(pred, b, hh, ww, cx, cy, pw, ph);

        float best = 0.0f;
        int winner = -1, cnt = 0;
        bool inreg = false;
        for (int j = 0; j < nact; ++j) {
            int n = list[j];
            const float* o = sb[n];
            const int* oi = (const int*)o;
            if (ww < oi[8] || ww > oi[9] || hh < oi[10] || hh > oi[11]) continue;
            inreg = true;
            float v = iou_one(cx, cy, pw, ph, o[1], o[2], o[3], o[4]);
            float kept = (v > o[0]) ? v : 0.0f;
            if (kept > best) { best = kept; winner = n; cnt = 1; }
            else if (kept == best && kept > 0.0f) { cnt++; }
        }

        bool assigned = best > 0.0f;
        if (assigned) {
            if (cnt > 1) { c0 = c1 = c2 = 0.0f; }
            else {
                int cid = ((const int*)sb[winner])[7];
                c0 = (cid == 0) ? 1.0f : 0.0f;
                c1 = (cid == 1) ? 1.0f : 0.0f;
                c2 = (cid == 2) ? 1.0f : 0.0f;
            }
            const float* o = sb[winner];
            p0 = o[1]; p1 = o[2]; p2 = o[3]; p3 = o[4]; p4 = o[5]; p5 = o[6];
        } else {
            if (inreg) { c0 = c1 = c2 = 0.0f; }
            else { c0 = 1.0f; c1 = 0.0f; c2 = 0.0f; }
            p0 = p1 = p2 = p3 = p4 = p5 = 1.0f;
        }
    }

    // stage to LDS (stride-3: 2-way bank alias = free; stride-6: 4-way, minor)
    scls[row][col * 3 + 0] = c0;
    scls[row][col * 3 + 1] = c1;
    scls[row][col * 3 + 2] = c2;
    spts[row][col * 6 + 0] = p0;
    spts[row][col * 6 + 1] = p1;
    spts[row][col * 6 + 2] = p2;
    spts[row][col * 6 + 3] = p3;
    spts[row][col * 6 + 4] = p4;
    spts[row][col * 6 + 5] = p5;
    __syncthreads();

    const int HW = IMG_H * IMG_W;
    // cls: 4 rows x 48 float4 = 192 float4 (alignment: all offsets %4==0 floats)
    if (tid < 192) {
        int r = tid / 48, k = tid - r * 48;
        float4* dst = (float4*)(out_cls + ((size_t)b * HW + (size_t)(th0 + r) * IMG_W + tw0) * 3);
        dst[k] = ((const float4*)scls)[tid];
    }
    // pts: 4 rows x 96 float4 = 384 float4
    for (int idx = tid; idx < 384; idx += 256) {
        int r = idx / 96, k = idx - r * 96;
        float4* dst = (float4*)(out_pts + ((size_t)b * HW + (size_t)(th0 + r) * IMG_W + tw0) * 6);
        dst[k] = ((const float4*)spts)[idx];
    }
}

extern "C" void kernel_launch(void* const* d_in, const int* in_sizes, int n_in,
                              void* d_out, int out_size, void* d_ws, size_t ws_size,
                              hipStream_t stream) {
    // inputs: feat (unused), pred (4,4,384,640), bboxes (4,64,6), difficult_mode (1)
    const float* pred = (const float*)d_in[1];
    const float* bboxes = (const float*)d_in[2];
    const int* dmode = (const int*)d_in[3];
    const int HW = IMG_H * IMG_W;
    float* out_cls = (float*)d_out;                       // (4,384,640,3)
    float* out_pts = (float*)d_out + (size_t)BS * HW * 3; // (4,384,640,6)
    float* pairws = (float*)d_ws;                         // 256 * 16 floats

    pair_kernel<<<dim3(BS * NBOX), dim3(PAIR_TPB), 0, stream>>>(pred, bboxes, dmode, pairws);
    pixel_kernel<<<dim3(TILES_X * TILES_Y, BS), dim3(256), 0, stream>>>(pred, pairws,
                                                                        out_cls, out_pts);
}

// Round 7
// 108.598 us; speedup vs baseline: 1.7595x; 1.0058x over previous
//
#include <hip/hip_runtime.h>

// Disable FMA contraction for the entire TU so IoU/decoding produce
// bitwise-identical results in both kernels (the top-dk selection uses
// strict > against the threshold, so bit-exactness matters).
#pragma clang fp contract(off)

#define IMG_W 640
#define IMG_H 384
#define NBOX 64
#define BS 4
#define PAIR_STRIDE 16
#define CAP 12544   // 112*112 >= worst-case region cells (<=103*103)
#define PAIR_TPB 1024
#define NHIST 8     // sub-histograms to spread LDS atomic contention

#define TILE_W 64
#define TILE_H 4
#define TILES_X (IMG_W / TILE_W)   // 10
#define TILES_Y (IMG_H / TILE_H)   // 96

// native clang vector (HIP float4 is a class type -> rejected by
// __builtin_nontemporal_store; this one is accepted, same 16B layout)
typedef float f4 __attribute__((ext_vector_type(4)));

// IoU exactly as reference _boxes_iou.
__device__ __forceinline__ float iou_one(float cx, float cy, float w, float h,
                                         float gcx, float gcy, float gw, float gh) {
    float b1minx = cx - w / 2.0f;
    float b1maxx = cx + w / 2.0f;
    float b1miny = cy - h / 2.0f;
    float b1maxy = cy + h / 2.0f;
    float b2minx = gcx - gw / 2.0f;
    float b2maxx = gcx + gw / 2.0f;
    float b2miny = gcy - gh / 2.0f;
    float b2maxy = gcy + gh / 2.0f;
    float iw = fmaxf(fminf(b1maxx, b2maxx) - fmaxf(b1minx, b2minx), 0.0f);
    float ih = fmaxf(fminf(b1maxy, b2maxy) - fmaxf(b1miny, b2miny), 0.0f);
    float inter = iw * ih;
    float uni = w * h + gw * gh - inter;
    uni = fmaxf(uni, 1e-6f);
    return inter / uni;
}

// Decode one cell exactly as reference _decode.
__device__ __forceinline__ void decode_cell(const float* __restrict__ pred, int b,
                                            int hh, int ww,
                                            float& cx, float& cy, float& w, float& h) {
    const int HW = IMG_H * IMG_W;
    int base = ((b * 4) * IMG_H + hh) * IMG_W + ww;
    float p0 = pred[base];
    float p1 = pred[base + HW];
    float p2 = pred[base + 2 * HW];
    float p3 = pred[base + 3 * HW];
    float rx = ((float)ww + 0.5f) * 2.0f;   // (w+0.5)*(MODEL_W/W) = *2.0
    float ry = ((float)hh + 0.5f) * 2.0f;
    float x1 = p0 * 80.0f + rx;
    float y1 = p1 * 80.0f + ry;
    float x2 = p2 * 80.0f + rx;
    float y2 = p3 * 80.0f + ry;
    w = x2 - x1;
    h = y2 - y1;
    cx = x1 + w / 2.0f;
    cy = y1 + h / 2.0f;
}

// One block (1024 thr) per (b, n) pair: region IoUs in LDS, sum -> dk, exact
// radix select with parallel histogram rank-find, EARLY-EXIT to a direct
// gather-select once the surviving candidate set is <= 64 (typical after
// 2 of 4 passes, since IoUs cluster into ~5 exponent buckets).
__global__ __launch_bounds__(PAIR_TPB) void pair_kernel(const float* __restrict__ pred,
                                                        const float* __restrict__ bboxes,
                                                        const int* __restrict__ dmode,
                                                        float* __restrict__ pairws) {
    __shared__ float vals[CAP];                 // 50176 B
    __shared__ unsigned hist[NHIST][256];       // 8192 B
    __shared__ float redf[PAIR_TPB / 64];
    __shared__ unsigned redu[PAIR_TPB / 64];
    __shared__ unsigned wsum[4];
    __shared__ unsigned sb_bucket, sb_r, sb_cnt;
    __shared__ float cand[64];
    __shared__ unsigned cand_n;
    __shared__ float sthr;

    const int pair = blockIdx.x;
    const int b = pair >> 6;
    const int tid = threadIdx.x;

    const float* box = bboxes + pair * 6;
    float gx1 = box[0], gy1 = box[1], gx2 = box[2], gy2 = box[3];
    float gcls = box[4], gdiff = box[5];
    float gbw = gx2 - gx1;
    float gbh = gy2 - gy1;
    float gcx = gx1 + gbw / 2.0f;
    float gcy = gy1 + gbh / 2.0f;
    bool valid = (gbw * gbh) != 0.0f;

    // Region bounds, replicating reference float op order exactly.
    float mwf = floorf(fmaxf(gx1 * 640.0f / 1280.0f - 0.5f, 0.0f));
    float Mwf = ceilf(fminf(gx2 * 640.0f / 1280.0f - 0.5f, 639.0f));
    float mhf = floorf(fmaxf(gy1 * 384.0f / 768.0f - 0.5f, 0.0f));
    float Mhf = ceilf(fminf(gy2 * 384.0f / 768.0f - 0.5f, 383.0f));
    int wlo = (int)mwf, whi = (int)Mwf, hlo = (int)mhf, hhi = (int)Mhf;
    int rw = whi - wlo + 1;
    int rh = hhi - hlo + 1;
    int area = (valid && rw > 0 && rh > 0) ? rw * rh : 0;
    if (area > CAP) area = CAP;   // cannot trigger for harness inputs (<=10609)

    // Magic-number division for i/rw (exact: rw<=2^7, i<2^32, err < i/2^32 < 1)
    unsigned inv_rw = (rw > 1) ? (0xFFFFFFFFu / (unsigned)rw + 1u) : 0u;

    float lsum = 0.0f;
    unsigned lpos = 0;
    for (int i = tid; i < area; i += PAIR_TPB) {
        int q = (rw > 1) ? (int)(((unsigned long long)(unsigned)i * inv_rw) >> 32) : i;
        int hh = hlo + q;
        int ww = wlo + (i - q * rw);
        float cx, cy, pw, ph;
        decode_cell(pred, b, hh, ww, cx, cy, pw, ph);
        float val = iou_one(cx, cy, pw, ph, gcx, gcy, gbw, gbh);
        vals[i] = val;
        lsum += val;
        lpos += (val > 0.0f) ? 1u : 0u;
    }
    // wave reduce (64 lanes) then wave-0 combines the 16 wave partials
    for (int off = 32; off > 0; off >>= 1) {
        lsum += __shfl_down(lsum, off, 64);
        lpos += __shfl_down(lpos, off, 64);
    }
    int wave = tid >> 6;
    if ((tid & 63) == 0) { redf[wave] = lsum; redu[wave] = lpos; }
    __syncthreads();
    if (tid < 64) {
        float s = (tid < PAIR_TPB / 64) ? redf[tid] : 0.0f;
        unsigned p = (tid < PAIR_TPB / 64) ? redu[tid] : 0u;
        for (int off = 8; off > 0; off >>= 1) {
            s += __shfl_down(s, off, 64);
            p += __shfl_down(p, off, 64);
        }
        if (tid == 0) { redf[0] = s; redu[0] = p; }
    }
    __syncthreads();
    float sum = redf[0];
    unsigned npos = redu[0];
    int dk = (int)ceilf(fmaxf(sum, 1.0f));

    // Exact threshold: rank-dk (0-indexed desc) over full H*W array = positives
    // then zeros. If dk >= npos the threshold is 0.
    float thr = 0.0f;
    if ((unsigned)dk < npos) {
        unsigned prefix = 0;
        unsigned r = (unsigned)dk;
        unsigned cnt = npos;
        bool done = false;
        for (int shift = 24; shift >= 0; shift -= 8) {
            unsigned maskhi = (shift == 24) ? 0u : (0xFFFFFFFFu << (shift + 8));
            if (cnt <= 64u) {
                // Gather the <=64 candidates matching prefix, rank-select direct.
                if (tid == 0) cand_n = 0;
                __syncthreads();
                for (int i = tid; i < area; i += PAIR_TPB) {
                    float val = vals[i];
                    if (val > 0.0f) {
                        unsigned u = __float_as_uint(val);
                        if ((u & maskhi) == prefix) {
                            unsigned p = atomicAdd(&cand_n, 1u);
                            cand[p] = val;
                        }
                    }
                }
                __syncthreads();
                if (tid < 64) {
                    unsigned c = cand_n;
                    if (tid < c) {
                        float mv = cand[tid];
                        unsigned g = 0, e = 0;
                        for (unsigned j = 0; j < c; ++j) {
                            float o = cand[j];
                            g += (o > mv) ? 1u : 0u;
                            e += (o == mv) ? 1u : 0u;
                        }
                        if (g <= r && r < g + e) sthr = mv;  // all matchers equal
                    }
                }
                __syncthreads();
                thr = sthr;
                done = true;
                break;
            }
            // zero the 8 sub-histograms (2048 words, 1024 threads)
            ((unsigned*)hist)[tid] = 0;
            ((unsigned*)hist)[tid + PAIR_TPB] = 0;
            __syncthreads();
            unsigned* myhist = hist[(tid >> 7) & (NHIST - 1)];
            for (int i = tid; i < area; i += PAIR_TPB) {
                float val = vals[i];
                if (val > 0.0f) {
                    unsigned u = __float_as_uint(val);
                    if ((u & maskhi) == prefix)
                        atomicAdd(&myhist[(u >> shift) & 255u], 1u);
                }
            }
            __syncthreads();
            // Parallel rank-find: thread t (<256) owns bucket 255-t so
            // ascending t == descending value order. Reversed prefix sum via
            // wave scan + 4-wave combine, then locate the bucket containing r.
            unsigned c = 0, incl = 0;
            if (tid < 256) {
                int bk = 255 - tid;
#pragma unroll
                for (int j = 0; j < NHIST; ++j) c += hist[j][bk];
                incl = c;
                for (int off = 1; off < 64; off <<= 1) {
                    unsigned y = __shfl_up(incl, off, 64);
                    if ((tid & 63) >= off) incl += y;
                }
                if ((tid & 63) == 63) wsum[tid >> 6] = incl;
            }
            __syncthreads();
            if (tid < 256) {
                unsigned pre = 0;
                int w = tid >> 6;
                for (int j = 0; j < w; ++j) pre += wsum[j];
                incl += pre;
                unsigned excl = incl - c;
                if (r >= excl && r < incl) {   // exactly one thread matches
                    sb_bucket = (unsigned)(255 - tid);
                    sb_r = r - excl;
                    sb_cnt = c;
                }
            }
            __syncthreads();
            prefix |= sb_bucket << shift;
            r = sb_r;
            cnt = sb_cnt;
            __syncthreads();   // protect hist/wsum reuse next pass
        }
        // If all 4 passes ran without an early exit, the full 32-bit prefix
        // IS the rank value (cnt>64 identical duplicates).
        if (!done) thr = __uint_as_float(prefix);
    }

    if (tid == 0) {
        float* o = pairws + pair * PAIR_STRIDE;
        int* oi = (int*)o;
        o[0] = thr;
        o[1] = gcx; o[2] = gcy; o[3] = gbw; o[4] = gbh;
        o[5] = (*dmode != 0) ? ((gdiff >= 0.625f) ? 1.0f : 0.0f) : 1.0f;
        o[6] = 1.0f / sqrtf((float)dk);          // lam = dk^-0.5
        oi[7] = (int)gcls + 1;                   // class id
        oi[8] = wlo; oi[9] = whi; oi[10] = hlo; oi[11] = hhi;
        oi[12] = valid ? 1 : 0;
    }
}

// One block per 64x4 pixel tile: wave-0 prunes the 64 boxes against the tile
// rect into a compacted LDS list (order-preserving -> argmax semantics kept),
// each thread resolves its pixel over the short active list (per-pixel rect
// pre-check skips the pred read entirely for background pixels), then outputs
// are staged in LDS and streamed out as non-temporal float4s.
__global__ __launch_bounds__(256) void pixel_kernel(const float* __restrict__ pred,
                                                    const float* __restrict__ pairws,
                                                    float* __restrict__ out_cls,
                                                    float* __restrict__ out_pts) {
    __shared__ __align__(16) float sb[NBOX][PAIR_STRIDE];        // 4 KB
    __shared__ int list[NBOX];
    __shared__ int nact_s;
    __shared__ __align__(16) float scls[TILE_H][TILE_W * 3];     // 3 KB
    __shared__ __align__(16) float spts[TILE_H][TILE_W * 6];     // 6 KB

    const int b = blockIdx.y;
    const int tid = threadIdx.x;
    ((f4*)sb)[tid] = ((const f4*)(pairws + b * NBOX * PAIR_STRIDE))[tid];
    __syncthreads();

    const int tilex = blockIdx.x % TILES_X;
    const int tiley = blockIdx.x / TILES_X;
    const int tw0 = tilex * TILE_W, tw1 = tw0 + TILE_W - 1;
    const int th0 = tiley * TILE_H, th1 = th0 + TILE_H - 1;

    // wave 0: prune + compact
    if (tid < 64) {
        const int* oi = (const int*)sb[tid];
        bool ok = oi[12] && oi[9] >= tw0 && oi[8] <= tw1 && oi[11] >= th0 && oi[10] <= th1;
        unsigned long long mask = __ballot(ok);
        if (ok) {
            int pos = __popcll(mask & ((1ull << tid) - 1ull));
            list[pos] = tid;
        }
        if (tid == 0) nact_s = __popcll(mask);
    }
    __syncthreads();
    const int nact = nact_s;

    const int col = tid & (TILE_W - 1);
    const int row = tid >> 6;                  // 0..3
    const int ww = tw0 + col;
    const int hh = th0 + row;

    float c0 = 1.0f, c1 = 0.0f, c2 = 0.0f;
    float p0 = 1.0f, p1 = 1.0f, p2 = 1.0f, p3 = 1.0f, p4 = 1.0f, p5 = 1.0f;

    if (nact > 0) {
        // Per-pixel rect pre-check: find boxes whose region contains this
        // pixel BEFORE touching pred. Most pixels hit zero boxes.
        unsigned long long hits = 0ull;
        for (int j = 0; j < nact; ++j) {
            const int* oi = (const int*)sb[list[j]];
            bool in = (ww >= oi[8] && ww <= oi[9] && hh >= oi[10] && hh <= oi[11]);
            hits |= in ? (1ull << j) : 0ull;
        }

        if (hits != 0ull) {
            float cx, cy, pw, ph;
            decode_cell(pred, b, hh, ww, cx, cy, pw, ph);

            float best = 0.0f;
            int winner = -1, cnt = 0;
            unsigned long long m = hits;
            while (m) {
                int j = __ffsll((unsigned long long)m) - 1;
                m &= m - 1ull;
                int n = list[j];
                const float* o = sb[n];
                float v = iou_one(cx, cy, pw, ph, o[1], o[2], o[3], o[4]);
                float kept = (v > o[0]) ? v : 0.0f;
                if (kept > best) { best = kept; winner = n; cnt = 1; }
                else if (kept == best && kept > 0.0f) { cnt++; }
            }

            bool assigned = best > 0.0f;
            if (assigned) {
                if (cnt > 1) { c0 = c1 = c2 = 0.0f; }
                else {
                    int cid = ((const int*)sb[winner])[7];
                    c0 = (cid == 0) ? 1.0f : 0.0f;
                    c1 = (cid == 1) ? 1.0f : 0.0f;
                    c2 = (cid == 2) ? 1.0f : 0.0f;
                }
                const float* o = sb[winner];
                p0 = o[1]; p1 = o[2]; p2 = o[3]; p3 = o[4]; p4 = o[5]; p5 = o[6];
            } else {
                // in-region but nothing kept: cls all-zero, pts default 1
                c0 = c1 = c2 = 0.0f;
            }
        }
        // hits == 0: background defaults already set
    }

    // stage to LDS (stride-3: 2-way bank alias = free; stride-6: 4-way, minor)
    scls[row][col * 3 + 0] = c0;
    scls[row][col * 3 + 1] = c1;
    scls[row][col * 3 + 2] = c2;
    spts[row][col * 6 + 0] = p0;
    spts[row][col * 6 + 1] = p1;
    spts[row][col * 6 + 2] = p2;
    spts[row][col * 6 + 3] = p3;
    spts[row][col * 6 + 4] = p4;
    spts[row][col * 6 + 5] = p5;
    __syncthreads();

    const int HW = IMG_H * IMG_W;
    // cls: 4 rows x 48 float4 = 192 float4 (alignment: all offsets %4==0 floats)
    if (tid < 192) {
        int r = tid / 48, k = tid - r * 48;
        f4* dst = (f4*)(out_cls + ((size_t)b * HW + (size_t)(th0 + r) * IMG_W + tw0) * 3);
        __builtin_nontemporal_store(((const f4*)scls)[tid], &dst[k]);
    }
    // pts: 4 rows x 96 float4 = 384 float4
    for (int idx = tid; idx < 384; idx += 256) {
        int r = idx / 96, k = idx - r * 96;
        f4* dst = (f4*)(out_pts + ((size_t)b * HW + (size_t)(th0 + r) * IMG_W + tw0) * 6);
        __builtin_nontemporal_store(((const f4*)spts)[idx], &dst[k]);
    }
}

extern "C" void kernel_launch(void* const* d_in, const int* in_sizes, int n_in,
                              void* d_out, int out_size, void* d_ws, size_t ws_size,
                              hipStream_t stream) {
    // inputs: feat (unused), pred (4,4,384,640), bboxes (4,64,6), difficult_mode (1)
    const float* pred = (const float*)d_in[1];
    const float* bboxes = (const float*)d_in[2];
    const int* dmode = (const int*)d_in[3];
    const int HW = IMG_H * IMG_W;
    float* out_cls = (float*)d_out;                       // (4,384,640,3)
    float* out_pts = (float*)d_out + (size_t)BS * HW * 3; // (4,384,640,6)
    float* pairws = (float*)d_ws;                         // 256 * 16 floats

    pair_kernel<<<dim3(BS * NBOX), dim3(PAIR_TPB), 0, stream>>>(pred, bboxes, dmode, pairws);
    pixel_kernel<<<dim3(TILES_X * TILES_Y, BS), dim3(256), 0, stream>>>(pred, pairws,
                                                                        out_cls, out_pts);
}